// Round 5
// baseline (174.841 us; speedup 1.0000x reference)
//
#include <hip/hip_runtime.h>
#include <hip/hip_cooperative_groups.h>
#include <hip/hip_bf16.h>
#include <math.h>

// y[b,l,d] = x[b,l,d] * softplus((x@W1+b1)[b,l,d]) * sum_n((x@W2+b2)*(x@W3+b3))[b,l,n]

namespace cg = cooperative_groups;

namespace {

constexpr int Dd   = 1024;
constexpr int ROWS = 8192;

typedef __bf16 bf16x8 __attribute__((ext_vector_type(8)));
typedef float  floatx4 __attribute__((ext_vector_type(4)));

__device__ __forceinline__ float softplus_fast(float v) {
    float l = __logf(1.0f + __expf(v));
    return v > 15.0f ? v : l;
}
__device__ __forceinline__ float bf_lo(unsigned short u) {
    union { unsigned q; float f; } c; c.q = ((unsigned)u) << 16; return c.f;
}

// direct global->LDS DMA, 16B per lane (global_load_lds_dwordx4).
__device__ __forceinline__ void gld_lds16(const __bf16* g, __bf16* l) {
    __builtin_amdgcn_global_load_lds(
        (const __attribute__((address_space(1))) void*)g,
        (__attribute__((address_space(3))) void*)l, 16, 0, 0);
}

#define BAR()    asm volatile("s_barrier" ::: "memory")
#define LGKM0()  asm volatile("s_waitcnt lgkmcnt(0)" ::: "memory")
#define VMCNT(n) asm volatile("s_waitcnt vmcnt(" #n ")" ::: "memory")

// ---------------------------------------------------------------------------
// Fused cooperative kernel: 256 blocks x 512 threads, 144KB LDS (1 block/CU,
// all 256 co-resident -> grid.sync valid).
//
// Phase A (prep, per block):
//   - W2/W3 [k][16] fp32 -> per-block LDS bf16 transposed [16][1032] (pad 8:
//     row stride 2064B -> n,n+8 share a bank = 2-way/free). Replaces the old
//     standalone w23 kernel (no cross-block ordering needed).
//   - One 64x64 W1 -> W1t transpose tile per block (256 tiles total).
//   - 32 rows of x: fp32 -> bf16 Xb + S[row] via MFMA vs LDS W2t/W3t frags.
//     8 waves = 2 row-groups x 4-wave K-split (verbatim R4 prep arithmetic).
// grid.sync() (cooperative groups; fences make Xb/W1t/Sv device-visible).
// Phase B (gemm): R4 kernel verbatim — BM=256xBN=128, BK=64 as two 32-halves,
//   4Mx2N waves (64x64/wave), 6-deep half-tile LDS rings, counted vmcnt(12)
//   ladder, XOR chunk-swizzle both sides, XCD-pinned A-panels
//   (rb ≡ blockIdx%8 mod 8 -> per-XCD working set = 4MB = L2), fused epilogue.
// ---------------------------------------------------------------------------
#define MF(mt, nt, a_, b_) \
    acc[mt][nt] = __builtin_amdgcn_mfma_f32_16x16x32_bf16(a_, b_, acc[mt][nt], 0, 0, 0)
#define MFMA16() do { \
    __builtin_amdgcn_s_setprio(1); \
    MF(0, 0, af0, bf0); MF(0, 1, af0, bf1); MF(0, 2, af0, bf2); MF(0, 3, af0, bf3); \
    MF(1, 0, af1, bf0); MF(1, 1, af1, bf1); MF(1, 2, af1, bf2); MF(1, 3, af1, bf3); \
    MF(2, 0, af2, bf0); MF(2, 1, af2, bf1); MF(2, 2, af2, bf2); MF(2, 3, af2, bf3); \
    MF(3, 0, af3, bf0); MF(3, 1, af3, bf1); MF(3, 2, af3, bf2); MF(3, 3, af3, bf3); \
    __builtin_amdgcn_s_setprio(0); } while (0)

#define TILE(B0_, B1_, NX1_, KA_, KB_, S1_, S2_, N1_, N2_) do { \
    bf16x8 af0, af1, af2, af3, bf0, bf1, bf2, bf3; \
    /* P0: kh0, 16 MFMA */ \
    af0 = rdA(B0_, 0); af1 = rdA(B0_, 1); af2 = rdA(B0_, 2); af3 = rdA(B0_, 3); \
    bf0 = rdB(B0_, 0); bf1 = rdB(B0_, 1); bf2 = rdB(B0_, 2); bf3 = rdB(B0_, 3); \
    if (S1_) { stageA(NX1_, KA_); stageB(NX1_, KA_); } \
    BAR(); LGKM0(); MFMA16(); VMCNT(N1_); BAR(); \
    /* P1: kh1, 16 MFMA */ \
    af0 = rdA(B1_, 0); af1 = rdA(B1_, 1); af2 = rdA(B1_, 2); af3 = rdA(B1_, 3); \
    bf0 = rdB(B1_, 0); bf1 = rdB(B1_, 1); bf2 = rdB(B1_, 2); bf3 = rdB(B1_, 3); \
    if (S2_) { stageA(B0_, KB_); stageB(B0_, KB_); } \
    BAR(); LGKM0(); MFMA16(); VMCNT(N2_); BAR(); \
} while (0)

__global__ __launch_bounds__(512, 2) void fused_kernel(
    const float* __restrict__ X,  const float* __restrict__ W1,
    const float* __restrict__ b1, const float* __restrict__ W2,
    const float* __restrict__ b2, const float* __restrict__ W3,
    const float* __restrict__ b3, __bf16* __restrict__ Xb,
    __bf16* __restrict__ W1t, float* __restrict__ Sv,
    float* __restrict__ Y)
{
    // Phase B ring: A 6x8192 bf16 [0,49152), B 6x4096 bf16 [49152,73728).
    // Phase A union: W2L @0 (16512 elems), W3L @16512, red @ byte 66048
    // (8x2x16x16 f32), tile @ byte 82432 (64x66 bf16) — total 90880B < 144KB.
    __shared__ __attribute__((aligned(16))) __bf16 lds[73728];
    const int t = threadIdx.x, lane = t & 63;
    const int l15 = lane & 15, quad = lane >> 4;
    const int blk = blockIdx.x;

    // ================= phase A: prep =================
    {
        __bf16* W2L = lds;                 // [16][1032] bf16
        __bf16* W3L = lds + 16512;         // [16][1032] bf16
        float*  redL = (float*)((char*)lds + 66048);           // [8][2][16][16]
        __bf16 (*tileL)[66] = (__bf16(*)[66])((char*)lds + 82432);

        // W2/W3 -> LDS transposed bf16 (coalesced float4 reads, b16 scatter)
        const float4* W2v = (const float4*)W2;
        const float4* W3v = (const float4*)W3;
        #pragma unroll
        for (int jj = 0; jj < 8; ++jj) {
            const int q = t + jj * 512;            // q in [0,4096)
            const int k = q >> 2, n0 = (q & 3) << 2;
            const float4 v2 = W2v[q];
            const float4 v3 = W3v[q];
            W2L[(n0 + 0) * 1032 + k] = (__bf16)v2.x;
            W2L[(n0 + 1) * 1032 + k] = (__bf16)v2.y;
            W2L[(n0 + 2) * 1032 + k] = (__bf16)v2.z;
            W2L[(n0 + 3) * 1032 + k] = (__bf16)v2.w;
            W3L[(n0 + 0) * 1032 + k] = (__bf16)v3.x;
            W3L[(n0 + 1) * 1032 + k] = (__bf16)v3.y;
            W3L[(n0 + 2) * 1032 + k] = (__bf16)v3.z;
            W3L[(n0 + 3) * 1032 + k] = (__bf16)v3.w;
        }
        // W1 64x64 tile: block blk -> (bi, bj)
        const int bi = blk >> 4, bj = blk & 15;
        const int tc = t & 63, r8 = t >> 6;
        #pragma unroll
        for (int i = 0; i < 8; ++i) {
            const int r = i * 8 + r8;
            tileL[r][tc] = (__bf16)W1[(size_t)(bi * 64 + r) * Dd + bj * 64 + tc];
        }
        __syncthreads();
        #pragma unroll
        for (int i = 0; i < 8; ++i) {
            const int r = i * 8 + r8;
            W1t[(size_t)(bj * 64 + r) * Dd + bi * 64 + tc] = tileL[tc][r];
        }

        // x -> Xb + S for rows [blk*32, blk*32+32): 2 groups x 4-wave K-split
        const int w = t >> 6, g = w >> 2, kw = (w & 3) * 256;
        const int row0p = blk * 32;
        const size_t xoff = (size_t)(row0p + g * 16 + l15) * Dd;

        floatx4 acc0 = {0.f, 0.f, 0.f, 0.f}, acc1 = {0.f, 0.f, 0.f, 0.f};
        #pragma unroll
        for (int ks = 0; ks < 8; ++ks) {
            const int k0 = kw + ks * 32 + quad * 8;
            const float4 xa = *(const float4*)&X[xoff + k0];
            const float4 xc = *(const float4*)&X[xoff + k0 + 4];
            bf16x8 af;
            af[0] = (__bf16)xa.x; af[1] = (__bf16)xa.y;
            af[2] = (__bf16)xa.z; af[3] = (__bf16)xa.w;
            af[4] = (__bf16)xc.x; af[5] = (__bf16)xc.y;
            af[6] = (__bf16)xc.z; af[7] = (__bf16)xc.w;
            *(bf16x8*)&Xb[xoff + k0] = af;
            const bf16x8 w2f = *(const bf16x8*)&W2L[l15 * 1032 + k0];
            const bf16x8 w3f = *(const bf16x8*)&W3L[l15 * 1032 + k0];
            acc0 = __builtin_amdgcn_mfma_f32_16x16x32_bf16(af, w2f, acc0, 0, 0, 0);
            acc1 = __builtin_amdgcn_mfma_f32_16x16x32_bf16(af, w3f, acc1, 0, 0, 0);
        }
        #pragma unroll
        for (int r = 0; r < 4; ++r) {
            redL[w * 512 + (quad * 4 + r) * 16 + l15]       = acc0[r];
            redL[w * 512 + 256 + (quad * 4 + r) * 16 + l15] = acc1[r];
        }
        __syncthreads();
        {
            const int g2 = t >> 8, tt = t & 255, r = tt >> 4, n = tt & 15;
            float Bv = b2[n], Cv = b3[n];
            #pragma unroll
            for (int ww = 0; ww < 4; ++ww) {
                Bv += redL[(g2 * 4 + ww) * 512 + r * 16 + n];
                Cv += redL[(g2 * 4 + ww) * 512 + 256 + r * 16 + n];
            }
            float pp = Bv * Cv;
            pp += __shfl_xor(pp, 1); pp += __shfl_xor(pp, 2);
            pp += __shfl_xor(pp, 4); pp += __shfl_xor(pp, 8);
            if (n == 0) Sv[row0p + g2 * 16 + r] = pp;
        }
    }

    cg::this_grid().sync();

    // ================= phase B: gemm (R4 verbatim) =================
    {
        const int w = t >> 6, wm = w & 3, wn = w >> 2;   // 4M x 2N wave grid
        const int xcd = blk & 7, loc = blk >> 3;
        const int rb = xcd + 8 * (loc & 3);
        const int cb = loc >> 2;
        const int row0 = rb * 256, col0 = cb * 128;

        floatx4 acc[4][4] = {};

        const __bf16* gAs[2]; int dAs[2];
        #pragma unroll
        for (int i = 0; i < 2; ++i) {
            const int d = i * 512 + t, r = d >> 2, cp = d & 3, c = cp ^ ((r >> 1) & 3);
            gAs[i] = Xb + (size_t)(row0 + r) * Dd + c * 8;
            dAs[i] = d * 8;
        }
        const __bf16* gBs; int dBs;
        {
            const int d = t, r = d >> 2, cp = d & 3, c = cp ^ ((r >> 1) & 3);
            gBs = W1t + (size_t)(col0 + r) * Dd + c * 8;
            dBs = d * 8;
        }

        auto stageA = [&](int slot, int kb) {
            #pragma unroll
            for (int i = 0; i < 2; ++i)
                gld_lds16(gAs[i] + kb, &lds[slot * 8192 + dAs[i]]);
        };
        auto stageB = [&](int slot, int kb) {
            gld_lds16(gBs + kb, &lds[49152 + slot * 4096 + dBs]);
        };

        const int sc  = (quad ^ ((l15 >> 1) & 3)) * 8;
        const int aro = (wm * 64 + l15) * 32 + sc;    // + mt*512
        const int bro = (wn * 64 + l15) * 32 + sc;    // + nt*512

        auto rdA = [&](int slot, int mt) {
            return *(const bf16x8*)&lds[slot * 8192 + aro + mt * 512];
        };
        auto rdB = [&](int slot, int nt) {
            return *(const bf16x8*)&lds[49152 + slot * 4096 + bro + nt * 512];
        };

        // prologue: issue 0:kh0..2:kh0 (15 loads, FIFO); wait 0:kh0 landed.
        // (any residual phase-A stores ahead in the FIFO only tighten the wait)
        stageA(0, 0);   stageB(0, 0);
        stageA(1, 32);  stageB(1, 32);
        stageA(2, 64);  stageB(2, 64);
        stageA(3, 96);  stageB(3, 96);
        stageA(4, 128); stageB(4, 128);
        VMCNT(12); BAR();

        #pragma unroll 1
        for (int uu = 0; uu < 4; ++uu) {
            const int ku = uu * 192;
            TILE(0, 1, 5, ku + 160, ku + 192, true, true, 12, 12);
            TILE(2, 3, 1, ku + 224, ku + 256, true, true, 12, 12);
            TILE(4, 5, 3, ku + 288, ku + 320, true, true, 12, 12);
        }
        TILE(0, 1, 5, 928, 960, true,  true,  12, 12);  // u=12
        TILE(2, 3, 1, 992, 0,   true,  false, 12, 9);   // u=13
        TILE(4, 5, 3, 0,   0,   false, false, 6,  3);   // u=14
        TILE(0, 1, 5, 0,   0,   false, false, 0,  0);   // u=15

        // epilogue
        float bias[4];
        #pragma unroll
        for (int nt = 0; nt < 4; ++nt) bias[nt] = b1[col0 + wn * 64 + nt * 16 + l15];

        #pragma unroll
        for (int mt = 0; mt < 4; ++mt) {
            #pragma unroll
            for (int rr = 0; rr < 4; ++rr) {
                const int row = row0 + wm * 64 + mt * 16 + quad * 4 + rr;
                const float sv = Sv[row];
                const unsigned short* xrow =
                    (const unsigned short*)(Xb + (size_t)row * Dd + col0);
                float* yrow = Y + (size_t)row * Dd + col0;
                #pragma unroll
                for (int nt = 0; nt < 4; ++nt) {
                    const int cl = wn * 64 + nt * 16 + l15;
                    const float v  = acc[mt][nt][rr] + bias[nt];
                    const float sp = softplus_fast(v);
                    yrow[cl] = bf_lo(xrow[cl]) * sp * sv;
                }
            }
        }
    }
}

} // namespace

extern "C" void kernel_launch(void* const* d_in, const int* in_sizes, int n_in,
                              void* d_out, int out_size, void* d_ws, size_t ws_size,
                              hipStream_t stream)
{
    const float* X  = (const float*)d_in[0];
    const float* W1 = (const float*)d_in[1];
    const float* b1 = (const float*)d_in[2];
    const float* W2 = (const float*)d_in[3];
    const float* b2 = (const float*)d_in[4];
    const float* W3 = (const float*)d_in[5];
    const float* b3 = (const float*)d_in[6];
    // d_in[7] = A is dead code in the reference.
    float* Y = (float*)d_out;

    // workspace: Xb 16MB | W1t 2MB | Sv 32KB
    char* ws = (char*)d_ws;
    __bf16* Xb  = (__bf16*)ws;
    __bf16* W1t = (__bf16*)(ws + 16777216);
    float*  Sv  = (float*) (ws + 16777216 + 2097152);

    void* args[] = {
        (void*)&X, (void*)&W1, (void*)&b1, (void*)&W2, (void*)&b2,
        (void*)&W3, (void*)&b3, (void*)&Xb, (void*)&W1t, (void*)&Sv, (void*)&Y
    };
    hipLaunchCooperativeKernel(reinterpret_cast<void*>(fused_kernel),
                               dim3(256), dim3(512), args, 0, stream);
}

// Round 6
// 128.253 us; speedup vs baseline: 1.3632x; 1.3632x over previous
//
#include <hip/hip_runtime.h>
#include <hip/hip_bf16.h>
#include <math.h>

// y[b,l,d] = x[b,l,d] * softplus((x@W1+b1)[b,l,d]) * sum_n((x@W2+b2)*(x@W3+b3))[b,l,n]

namespace {

constexpr int Dd   = 1024;
constexpr int ROWS = 8192;

typedef __bf16 bf16x8 __attribute__((ext_vector_type(8)));
typedef float  floatx4 __attribute__((ext_vector_type(4)));

__device__ __forceinline__ float softplus_fast(float v) {
    float l = __logf(1.0f + __expf(v));
    return v > 15.0f ? v : l;
}
__device__ __forceinline__ float bf_lo(unsigned short u) {
    union { unsigned q; float f; } c; c.q = ((unsigned)u) << 16; return c.f;
}

// direct global->LDS DMA, 16B per lane (global_load_lds_dwordx4).
__device__ __forceinline__ void gld_lds16(const __bf16* g, __bf16* l) {
    __builtin_amdgcn_global_load_lds(
        (const __attribute__((address_space(1))) void*)g,
        (__attribute__((address_space(3))) void*)l, 16, 0, 0);
}

#define BAR()    asm volatile("s_barrier" ::: "memory")
#define LGKM0()  asm volatile("s_waitcnt lgkmcnt(0)" ::: "memory")
#define VMCNT(n) asm volatile("s_waitcnt vmcnt(" #n ")" ::: "memory")

// ---------------------------------------------------------------------------
// w23: grid 16 — W2,W3 [k][16] fp32 -> W2t,W3t [16][k] bf16.
// ---------------------------------------------------------------------------
__global__ __launch_bounds__(256) void w23_kernel(
    const float* __restrict__ W2, const float* __restrict__ W3,
    __bf16* __restrict__ W2t, __bf16* __restrict__ W3t)
{
    const int t  = threadIdx.x;
    const int n  = t >> 4;
    const int k0 = blockIdx.x * 64 + (t & 15) * 4;
    ushort4 a, b;
    union { __bf16 h; unsigned short u; } c;
    c.h = (__bf16)W2[(size_t)(k0 + 0) * 16 + n]; a.x = c.u;
    c.h = (__bf16)W2[(size_t)(k0 + 1) * 16 + n]; a.y = c.u;
    c.h = (__bf16)W2[(size_t)(k0 + 2) * 16 + n]; a.z = c.u;
    c.h = (__bf16)W2[(size_t)(k0 + 3) * 16 + n]; a.w = c.u;
    c.h = (__bf16)W3[(size_t)(k0 + 0) * 16 + n]; b.x = c.u;
    c.h = (__bf16)W3[(size_t)(k0 + 1) * 16 + n]; b.y = c.u;
    c.h = (__bf16)W3[(size_t)(k0 + 2) * 16 + n]; b.z = c.u;
    c.h = (__bf16)W3[(size_t)(k0 + 3) * 16 + n]; b.w = c.u;
    *(ushort4*)&W2t[(size_t)n * Dd + k0] = a;
    *(ushort4*)&W3t[(size_t)n * Dd + k0] = b;
}

// ---------------------------------------------------------------------------
// prep: blocks 0..511 — x fp32 -> bf16 Xb + S-vector via MFMA vs W2t/W3t.
//       blocks 512..767 — W1 transpose -> W1t bf16 (ushort4 stores, R6).
// ---------------------------------------------------------------------------
__global__ __launch_bounds__(256, 4) void prep_kernel(
    const float* __restrict__ X, const float* __restrict__ W1,
    const __bf16* __restrict__ W2t, const float* __restrict__ b2,
    const __bf16* __restrict__ W3t, const float* __restrict__ b3,
    __bf16* __restrict__ Xb, __bf16* __restrict__ W1t, float* __restrict__ Sv)
{
    const int t = threadIdx.x;

    if (blockIdx.x >= 512) {
        __shared__ __bf16 tile[64][66];
        const int bidx = blockIdx.x - 512;
        const int bi = bidx >> 4, bj = bidx & 15;
        const int c = t & 63, r4 = t >> 6;
        #pragma unroll
        for (int i = 0; i < 16; ++i) {
            const int r = i * 4 + r4;
            tile[r][c] = (__bf16)W1[(size_t)(bi * 64 + r) * Dd + bj * 64 + c];
        }
        __syncthreads();
        // vectorized transposed store: thread -> (row rr per pass, 4 cols)
        const int rr = t >> 4;           // 0..15
        const int c4 = (t & 15) * 4;     // 0,4,..,60
        union { __bf16 h; unsigned short u; } cv;
        #pragma unroll
        for (int p = 0; p < 4; ++p) {
            const int r = p * 16 + rr;
            ushort4 v;
            cv.h = tile[c4 + 0][r]; v.x = cv.u;
            cv.h = tile[c4 + 1][r]; v.y = cv.u;
            cv.h = tile[c4 + 2][r]; v.z = cv.u;
            cv.h = tile[c4 + 3][r]; v.w = cv.u;
            *(ushort4*)&W1t[(size_t)(bj * 64 + r) * Dd + bi * 64 + c4] = v;
        }
        return;
    }

    __shared__ float red[4][2][16][16];   // [wave][B/C][row][n]
    const int w = t >> 6, lane = t & 63;
    const int l15 = lane & 15, quad = lane >> 4;
    const int row0 = blockIdx.x * 16;
    const int kw = w * 256;
    const size_t xoff = (size_t)(row0 + l15) * Dd;
    const size_t woff = (size_t)l15 * Dd;

    floatx4 acc0 = {0.f, 0.f, 0.f, 0.f}, acc1 = {0.f, 0.f, 0.f, 0.f};
    #pragma unroll
    for (int ks = 0; ks < 8; ++ks) {
        const int k0 = kw + ks * 32 + quad * 8;
        const float4 xa = *(const float4*)&X[xoff + k0];
        const float4 xb = *(const float4*)&X[xoff + k0 + 4];
        bf16x8 af;
        af[0] = (__bf16)xa.x; af[1] = (__bf16)xa.y;
        af[2] = (__bf16)xa.z; af[3] = (__bf16)xa.w;
        af[4] = (__bf16)xb.x; af[5] = (__bf16)xb.y;
        af[6] = (__bf16)xb.z; af[7] = (__bf16)xb.w;
        *(bf16x8*)&Xb[xoff + k0] = af;
        const bf16x8 w2f = *(const bf16x8*)&W2t[woff + k0];
        const bf16x8 w3f = *(const bf16x8*)&W3t[woff + k0];
        acc0 = __builtin_amdgcn_mfma_f32_16x16x32_bf16(af, w2f, acc0, 0, 0, 0);
        acc1 = __builtin_amdgcn_mfma_f32_16x16x32_bf16(af, w3f, acc1, 0, 0, 0);
    }
    #pragma unroll
    for (int r = 0; r < 4; ++r) {
        red[w][0][quad * 4 + r][l15] = acc0[r];
        red[w][1][quad * 4 + r][l15] = acc1[r];
    }
    __syncthreads();
    {
        const int r = t >> 4, n = t & 15;
        float B = b2[n], C = b3[n];
        #pragma unroll
        for (int ww = 0; ww < 4; ++ww) {
            B += red[ww][0][r][n];
            C += red[ww][1][r][n];
        }
        float p = B * C;
        p += __shfl_xor(p, 1); p += __shfl_xor(p, 2);
        p += __shfl_xor(p, 4); p += __shfl_xor(p, 8);
        if (n == 0) Sv[row0 + r] = p;
    }
}

// ---------------------------------------------------------------------------
// gemm (R4-verified): BM=256 x BN=128, BK=64 = two 32-halves. 8 waves as
// 4M x 2N, per-wave 64x64 (acc[4][4]). Per half-K ONE phase: {8x ds_read_b128
// | stage-issue -> BAR -> lgkmcnt(0) -> setprio(1) 16xMFMA setprio(0) ->
// vmcnt(12) -> BAR}. 6-deep half-tile rings (A 6x16KB, B 6x8KB = 144KB);
// counted vmcnt never drains in steady state. Slot discipline: tile u reads
// slots (2u)%6,(2u+1)%6; P0 stages (u+2):kh1 -> (2u+5)%6; P1 stages
// (u+3):kh0 -> (2u)%6. XOR swizzle chunk' = chunk ^ ((row>>1)&3) both sides.
// XCD-pinned A-panels: rb ≡ blockIdx%8 (mod 8) -> per-XCD working set =
// 4 A-panels + 8 B-panels = 4MB = L2 (R4: −4.2us).
// R6: Y stores are NONTEMPORAL — Y (32MB, never re-read) must not evict the
// pinned A/B panels from L2.
// ---------------------------------------------------------------------------
#define MF(mt, nt, a_, b_) \
    acc[mt][nt] = __builtin_amdgcn_mfma_f32_16x16x32_bf16(a_, b_, acc[mt][nt], 0, 0, 0)
#define MFMA16() do { \
    __builtin_amdgcn_s_setprio(1); \
    MF(0, 0, af0, bf0); MF(0, 1, af0, bf1); MF(0, 2, af0, bf2); MF(0, 3, af0, bf3); \
    MF(1, 0, af1, bf0); MF(1, 1, af1, bf1); MF(1, 2, af1, bf2); MF(1, 3, af1, bf3); \
    MF(2, 0, af2, bf0); MF(2, 1, af2, bf1); MF(2, 2, af2, bf2); MF(2, 3, af2, bf3); \
    MF(3, 0, af3, bf0); MF(3, 1, af3, bf1); MF(3, 2, af3, bf2); MF(3, 3, af3, bf3); \
    __builtin_amdgcn_s_setprio(0); } while (0)

#define TILE(B0_, B1_, NX1_, KA_, KB_, S1_, S2_, N1_, N2_) do { \
    bf16x8 af0, af1, af2, af3, bf0, bf1, bf2, bf3; \
    /* P0: kh0, 16 MFMA */ \
    af0 = rdA(B0_, 0); af1 = rdA(B0_, 1); af2 = rdA(B0_, 2); af3 = rdA(B0_, 3); \
    bf0 = rdB(B0_, 0); bf1 = rdB(B0_, 1); bf2 = rdB(B0_, 2); bf3 = rdB(B0_, 3); \
    if (S1_) { stageA(NX1_, KA_); stageB(NX1_, KA_); } \
    BAR(); LGKM0(); MFMA16(); VMCNT(N1_); BAR(); \
    /* P1: kh1, 16 MFMA */ \
    af0 = rdA(B1_, 0); af1 = rdA(B1_, 1); af2 = rdA(B1_, 2); af3 = rdA(B1_, 3); \
    bf0 = rdB(B1_, 0); bf1 = rdB(B1_, 1); bf2 = rdB(B1_, 2); bf3 = rdB(B1_, 3); \
    if (S2_) { stageA(B0_, KB_); stageB(B0_, KB_); } \
    BAR(); LGKM0(); MFMA16(); VMCNT(N2_); BAR(); \
} while (0)

__global__ __launch_bounds__(512, 2) void gemm_kernel(
    const __bf16* __restrict__ Xb, const __bf16* __restrict__ W1t,
    const float* __restrict__ Sv, const float* __restrict__ b1,
    float* __restrict__ Y)
{
    // A ring: 6 slots x 8192 bf16 (256 rows x 32 k) = 96KB at [0, 49152)
    // B ring: 6 slots x 4096 bf16 (128 rows x 32 k) = 48KB at [49152, 73728)
    __shared__ __attribute__((aligned(16))) __bf16 lds[73728];
    const int t = threadIdx.x, lane = t & 63;
    const int w = t >> 6, wm = w & 3, wn = w >> 2;   // 4M x 2N wave grid
    const int l15 = lane & 15, quad = lane >> 4;
    // XCD-pinned A-panels: xcd = blockIdx%8 (HW round-robin heuristic);
    // rb ≡ xcd (mod 8) -> this XCD's 4 A-panels + all 8 B-panels fit its L2.
    const int xcd = blockIdx.x & 7, loc = blockIdx.x >> 3;
    const int rb = xcd + 8 * (loc & 3);
    const int cb = loc >> 2;
    const int row0 = rb * 256, col0 = cb * 128;

    floatx4 acc[4][4] = {};

    // staging sources, pre-swizzled (m173): chunk d -> row r=d>>2, lds chunk
    // c'=d&3, global chunk c = c' ^ ((r>>1)&3). LDS dest linear (lane*16B).
    const __bf16* gAs[2]; int dAs[2];
    #pragma unroll
    for (int i = 0; i < 2; ++i) {
        const int d = i * 512 + t, r = d >> 2, cp = d & 3, c = cp ^ ((r >> 1) & 3);
        gAs[i] = Xb + (size_t)(row0 + r) * Dd + c * 8;
        dAs[i] = d * 8;
    }
    const __bf16* gBs; int dBs;
    {
        const int d = t, r = d >> 2, cp = d & 3, c = cp ^ ((r >> 1) & 3);
        gBs = W1t + (size_t)(col0 + r) * Dd + c * 8;
        dBs = d * 8;
    }

    auto stageA = [&](int slot, int kb) {
        #pragma unroll
        for (int i = 0; i < 2; ++i)
            gld_lds16(gAs[i] + kb, &lds[slot * 8192 + dAs[i]]);
    };
    auto stageB = [&](int slot, int kb) {
        gld_lds16(gBs + kb, &lds[49152 + slot * 4096 + dBs]);
    };

    // read side: swizzled chunk offset; (row>>1)&3 == (l15>>1)&3 for all frags
    const int sc  = (quad ^ ((l15 >> 1) & 3)) * 8;
    const int aro = (wm * 64 + l15) * 32 + sc;    // + mt*512
    const int bro = (wn * 64 + l15) * 32 + sc;    // + nt*512

    auto rdA = [&](int slot, int mt) {
        return *(const bf16x8*)&lds[slot * 8192 + aro + mt * 512];
    };
    auto rdB = [&](int slot, int nt) {
        return *(const bf16x8*)&lds[49152 + slot * 4096 + bro + nt * 512];
    };

    // prologue: issue 0:kh0, 0:kh1, 1:kh0, 1:kh1, 2:kh0 (15 loads, FIFO);
    // wait 0:kh0 landed (12 newer stay in flight).
    stageA(0, 0);   stageB(0, 0);
    stageA(1, 32);  stageB(1, 32);
    stageA(2, 64);  stageB(2, 64);
    stageA(3, 96);  stageB(3, 96);
    stageA(4, 128); stageB(4, 128);
    VMCNT(12); BAR();

    // main: u = 0..11 in groups of 3 (slot indices compile-time constant)
    #pragma unroll 1
    for (int uu = 0; uu < 4; ++uu) {
        const int ku = uu * 192;
        TILE(0, 1, 5, ku + 160, ku + 192, true, true, 12, 12);  // u=3uu+0
        TILE(2, 3, 1, ku + 224, ku + 256, true, true, 12, 12);  // u=3uu+1
        TILE(4, 5, 3, ku + 288, ku + 320, true, true, 12, 12);  // u=3uu+2
    }
    // tail (peeled, exact FIFO vmcnt ladder — R2/R3-verified counts):
    TILE(0, 1, 5, 928, 960, true,  true,  12, 12);  // u=12
    TILE(2, 3, 1, 992, 0,   true,  false, 12, 9);   // u=13: stage 15:kh1 only
    TILE(4, 5, 3, 0,   0,   false, false, 6,  3);   // u=14
    TILE(0, 1, 5, 0,   0,   false, false, 0,  0);   // u=15

    // epilogue: C/D frag layout col = l15, row = quad*4 + rr
    float bias[4];
    #pragma unroll
    for (int nt = 0; nt < 4; ++nt) bias[nt] = b1[col0 + wn * 64 + nt * 16 + l15];

    #pragma unroll
    for (int mt = 0; mt < 4; ++mt) {
        #pragma unroll
        for (int rr = 0; rr < 4; ++rr) {
            const int row = row0 + wm * 64 + mt * 16 + quad * 4 + rr;
            const float sv = Sv[row];
            const unsigned short* xrow =
                (const unsigned short*)(Xb + (size_t)row * Dd + col0);
            float* yrow = Y + (size_t)row * Dd + col0;
            #pragma unroll
            for (int nt = 0; nt < 4; ++nt) {
                const int cl = wn * 64 + nt * 16 + l15;
                const float v  = acc[mt][nt][rr] + bias[nt];
                const float sp = softplus_fast(v);
                // nontemporal: Y is write-once, never re-read; keep the
                // XCD-pinned A/B panels resident in L2.
                __builtin_nontemporal_store(bf_lo(xrow[cl]) * sp * sv,
                                            &yrow[cl]);
            }
        }
    }
}

} // namespace

extern "C" void kernel_launch(void* const* d_in, const int* in_sizes, int n_in,
                              void* d_out, int out_size, void* d_ws, size_t ws_size,
                              hipStream_t stream)
{
    const float* X  = (const float*)d_in[0];
    const float* W1 = (const float*)d_in[1];
    const float* b1 = (const float*)d_in[2];
    const float* W2 = (const float*)d_in[3];
    const float* b2 = (const float*)d_in[4];
    const float* W3 = (const float*)d_in[5];
    const float* b3 = (const float*)d_in[6];
    // d_in[7] = A is dead code in the reference.
    float* Y = (float*)d_out;

    // workspace: Xb 16MB | W1t 2MB | Sv 32KB | W2t 32KB | W3t 32KB
    char* ws = (char*)d_ws;
    __bf16* Xb  = (__bf16*)ws;
    __bf16* W1t = (__bf16*)(ws + 16777216);
    float*  Sv  = (float*) (ws + 16777216 + 2097152);
    __bf16* W2t = (__bf16*)(ws + 16777216 + 2097152 + 32768);
    __bf16* W3t = (__bf16*)(ws + 16777216 + 2097152 + 65536);

    hipLaunchKernelGGL(w23_kernel, dim3(16), dim3(256), 0, stream, W2, W3, W2t, W3t);
    hipLaunchKernelGGL(prep_kernel, dim3(768), dim3(256), 0, stream,
                       X, W1, W2t, b2, W3t, b3, Xb, W1t, Sv);
    hipLaunchKernelGGL(gemm_kernel, dim3((ROWS / 256) * (Dd / 128)), dim3(512), 0, stream,
                       Xb, W1t, Sv, b1, Y);
}